// Round 12
// baseline (475.846 us; speedup 1.0000x reference)
//
#include <hip/hip_runtime.h>
#include <math.h>

#define SCALEF 0.25f            // 1/sqrt(D=16)
#define LOG2E  1.4426950408889634f

typedef __attribute__((ext_vector_type(8))) short short8;
typedef __attribute__((ext_vector_type(4))) float f32x4;

__device__ __forceinline__ unsigned short f2bf(float x) {
  unsigned u = __float_as_uint(x);
  unsigned r = u + 0x7FFFu + ((u >> 16) & 1u);
  return (unsigned short)(r >> 16);
}
__device__ __forceinline__ float bf2f(unsigned short h) {
  return __uint_as_float(((unsigned)h) << 16);
}

// ======================= CSR build =======================
__global__ void k_hist(const int* __restrict__ dst, int* __restrict__ counts, int E) {
  int i = blockIdx.x * 256 + threadIdx.x;
  if (i < E) atomicAdd(&counts[dst[i]], 1);
}

// single-block exclusive scan over counts -> rowptr/cursor (replaces 3 kernels)
__global__ __launch_bounds__(1024) void k_scanone(const int* __restrict__ counts,
                                                  int* __restrict__ rowptr,
                                                  int* __restrict__ cursor, int n, int E) {
  __shared__ int sd[1024];
  const int t = threadIdx.x;
  const int per = (n + 1023) >> 10;
  const int base = t * per;
  int s = 0;
  for (int i = 0; i < per; ++i) {
    const int idx = base + i;
    if (idx < n) s += counts[idx];
  }
  sd[t] = s;
  __syncthreads();
  for (int off = 1; off < 1024; off <<= 1) {
    int x = (t >= off) ? sd[t - off] : 0;
    __syncthreads();
    sd[t] += x;
    __syncthreads();
  }
  int run = (t == 0) ? 0 : sd[t - 1];
  for (int i = 0; i < per; ++i) {
    const int idx = base + i;
    if (idx < n) {
      rowptr[idx] = run;
      cursor[idx] = run;
      run += counts[idx];
    }
  }
  if (t == 0) rowptr[n] = E;
}

// fused scatter+permute: place each edge directly at its CSR slot.
// esrcp holds BYTE offsets into the packed KV array (sn*256); EA -> bf16 row.
__global__ void k_scatperm(const int* __restrict__ esrc, const int* __restrict__ edst,
                           const float* __restrict__ EA, int* __restrict__ cursor,
                           int* __restrict__ esrcp, unsigned short* __restrict__ EAp, int E) {
  int i = blockIdx.x * 256 + threadIdx.x;
  if (i >= E) return;
  const int pos = atomicAdd(&cursor[edst[i]], 1);
  esrcp[pos] = esrc[i] * 256;
  const float4* s4 = (const float4*)(EA + ((size_t)i << 4));
  float4 a = s4[0], b = s4[1], c = s4[2], d = s4[3];
  union { unsigned short us[16]; uint4 u4[2]; } o;
  o.us[0] = f2bf(a.x); o.us[1] = f2bf(a.y); o.us[2] = f2bf(a.z); o.us[3] = f2bf(a.w);
  o.us[4] = f2bf(b.x); o.us[5] = f2bf(b.y); o.us[6] = f2bf(b.z); o.us[7] = f2bf(b.w);
  o.us[8] = f2bf(c.x); o.us[9] = f2bf(c.y); o.us[10] = f2bf(c.z); o.us[11] = f2bf(c.w);
  o.us[12] = f2bf(d.x); o.us[13] = f2bf(d.y); o.us[14] = f2bf(d.z); o.us[15] = f2bf(d.w);
  uint4* d4 = (uint4*)(EAp + ((size_t)pos << 4));
  d4[0] = o.u4[0]; d4[1] = o.u4[1];
}

// ======================= per-layer Wqt = (Wq @ M)*SCALE =======================
__global__ __launch_bounds__(256) void k_wqt(
    const float* __restrict__ Wq0, const float* __restrict__ bq0, const float* __restrict__ We0,
    const float* __restrict__ Wq, const float* __restrict__ bq, const float* __restrict__ We,
    float* __restrict__ Wqt, float* __restrict__ bqt) {
  const int l = blockIdx.x;
  const float* wq = (l == 0) ? Wq0 : Wq + (l - 1) * 4096;
  const float* bv = (l == 0) ? bq0 : bq + (l - 1) * 64;
  const float* we = (l == 0) ? We0 : We + (l - 1) * 1024;
  float* out  = Wqt + l * 4096;
  float* outb = bqt + l * 64;
  const int t = threadIdx.x;
  const int r = t >> 2;
  const int hh = t & 3;
  float wqr[16];
  #pragma unroll
  for (int d = 0; d < 16; ++d) wqr[d] = wq[r * 64 + hh * 16 + d];
  #pragma unroll
  for (int bb = 0; bb < 16; ++bb) {
    float s = 0.f;
    #pragma unroll
    for (int d = 0; d < 16; ++d) s += wqr[d] * we[bb * 64 + hh * 16 + d];
    out[r * 64 + hh * 16 + bb] = s * SCALEF;
  }
  if (r == 0) {
    #pragma unroll
    for (int bb = 0; bb < 16; ++bb) {
      float s = 0.f;
      #pragma unroll
      for (int d = 0; d < 16; ++d) s += bv[hh * 16 + d] * we[bb * 64 + hh * 16 + d];
      outb[hh * 16 + bb] = s * SCALEF;
    }
  }
}

// ======================= fused prep: weight transpose->bf16 + x->bf16 =======================
__global__ void k_prep(
    const float* __restrict__ x, unsigned short* __restrict__ xb, int n16,
    const float* __restrict__ Wq0, const float* __restrict__ Wk0, const float* __restrict__ Wv0,
    const float* __restrict__ Ws0,
    const float* __restrict__ Wq, const float* __restrict__ Wk, const float* __restrict__ Wv,
    const float* __restrict__ Ws, const float* __restrict__ Wqt,
    const float* __restrict__ bq0, const float* __restrict__ bk0, const float* __restrict__ bv0,
    const float* __restrict__ bs0,
    const float* __restrict__ bq, const float* __restrict__ bk, const float* __restrict__ bv,
    const float* __restrict__ bs, const float* __restrict__ bqt,
    unsigned short* __restrict__ WT, float* __restrict__ bcat) {
  const int id = blockIdx.x * 256 + threadIdx.x;
  if (id < n16) {
    float4 v = ((const float4*)x)[id];
    ushort4 o;
    o.x = f2bf(v.x); o.y = f2bf(v.y); o.z = f2bf(v.z); o.w = f2bf(v.w);
    ((ushort4*)xb)[id] = o;
  }
  if (id < 4 * 5 * 4096) {
    const int l = id / 20480;
    const int rem = id - l * 20480;
    const int mat = rem >> 12;
    const int idx = rem & 4095;
    const int k = idx >> 6;
    const int c = idx & 63;
    float v;
    if (mat == 0)      v = (l == 0) ? Wq0[idx] : Wq[(l - 1) * 4096 + idx];
    else if (mat == 1) v = (l == 0) ? Wk0[idx] : Wk[(l - 1) * 4096 + idx];
    else if (mat == 2) v = (l == 0) ? Wv0[idx] : Wv[(l - 1) * 4096 + idx];
    else if (mat == 3) v = (l == 0) ? Ws0[idx] : Ws[(l - 1) * 4096 + idx];
    else               v = Wqt[l * 4096 + idx];
    WT[(size_t)(l * 5 + mat) * 4096 + c * 64 + k] = f2bf(v);
    if (k == 0) {
      float b;
      if (mat == 0)      b = (l == 0) ? bq0[c] : bq[(l - 1) * 64 + c];
      else if (mat == 1) b = (l == 0) ? bk0[c] : bk[(l - 1) * 64 + c];
      else if (mat == 2) b = (l == 0) ? bv0[c] : bv[(l - 1) * 64 + c];
      else if (mat == 3) b = (l == 0) ? bs0[c] : bs[(l - 1) * 64 + c];
      else               b = bqt[l * 64 + c];
      bcat[(l * 5 + mat) * 64 + c] = b;
    }
  }
}

// ======================= node linear via MFMA =======================
// One wave per 16-row tile; all 5 matrices (40 MFMA) reuse the A fragments.
// K,V write interleaved into KV16 (uint per (node,col): K low / V high ushort).
__global__ __launch_bounds__(256) void k_linm(
    const unsigned short* __restrict__ Xb, const unsigned short* __restrict__ WT,
    const float* __restrict__ bcat,
    unsigned short* __restrict__ Qb, unsigned short* __restrict__ KV16,
    unsigned short* __restrict__ Sb, unsigned short* __restrict__ Tb, int n) {
  const int lane = threadIdx.x & 63;
  const int tile = blockIdx.x * 4 + (threadIdx.x >> 6);
  const int ntr = n >> 4;                    // N % 16 == 0
  if (tile >= ntr) return;
  const int r0 = tile << 4;
  const int c15 = lane & 15;
  const int kg = lane >> 4;                  // 0..3
  const int rbase = r0 + kg * 4;

  const unsigned short* xrow = Xb + (size_t)(r0 + c15) * 64 + kg * 8;
  const short8 a0 = *(const short8*)(xrow);
  const short8 a1 = *(const short8*)(xrow + 32);

  #pragma unroll
  for (int mat = 0; mat < 5; ++mat) {
    const unsigned short* wb = WT + ((size_t)mat << 12) + (size_t)c15 * 64 + kg * 8;
    f32x4 acc0 = {0.f, 0.f, 0.f, 0.f}, acc1 = acc0, acc2 = acc0, acc3 = acc0;
    {
      short8 b0 = *(const short8*)(wb);
      short8 b1 = *(const short8*)(wb + 32);
      acc0 = __builtin_amdgcn_mfma_f32_16x16x32_bf16(a0, b0, acc0, 0, 0, 0);
      acc0 = __builtin_amdgcn_mfma_f32_16x16x32_bf16(a1, b1, acc0, 0, 0, 0);
    }
    {
      short8 b0 = *(const short8*)(wb + 16 * 64);
      short8 b1 = *(const short8*)(wb + 16 * 64 + 32);
      acc1 = __builtin_amdgcn_mfma_f32_16x16x32_bf16(a0, b0, acc1, 0, 0, 0);
      acc1 = __builtin_amdgcn_mfma_f32_16x16x32_bf16(a1, b1, acc1, 0, 0, 0);
    }
    {
      short8 b0 = *(const short8*)(wb + 32 * 64);
      short8 b1 = *(const short8*)(wb + 32 * 64 + 32);
      acc2 = __builtin_amdgcn_mfma_f32_16x16x32_bf16(a0, b0, acc2, 0, 0, 0);
      acc2 = __builtin_amdgcn_mfma_f32_16x16x32_bf16(a1, b1, acc2, 0, 0, 0);
    }
    {
      short8 b0 = *(const short8*)(wb + 48 * 64);
      short8 b1 = *(const short8*)(wb + 48 * 64 + 32);
      acc3 = __builtin_amdgcn_mfma_f32_16x16x32_bf16(a0, b0, acc3, 0, 0, 0);
      acc3 = __builtin_amdgcn_mfma_f32_16x16x32_bf16(a1, b1, acc3, 0, 0, 0);
    }

    const float* bb = bcat + mat * 64;
    const float bi0 = bb[c15], bi1 = bb[16 + c15], bi2 = bb[32 + c15], bi3 = bb[48 + c15];

    if (mat == 1 || mat == 2) {
      unsigned short* O = KV16 + (mat == 2 ? 1 : 0);
      #pragma unroll
      for (int reg = 0; reg < 4; ++reg) {
        const size_t ro = (size_t)(rbase + reg) * 128;
        O[ro + 2 * c15]        = f2bf(acc0[reg] + bi0);
        O[ro + 2 * (16 + c15)] = f2bf(acc1[reg] + bi1);
        O[ro + 2 * (32 + c15)] = f2bf(acc2[reg] + bi2);
        O[ro + 2 * (48 + c15)] = f2bf(acc3[reg] + bi3);
      }
    } else {
      unsigned short* O = (mat == 0) ? Qb : (mat == 3) ? Sb : Tb;
      #pragma unroll
      for (int reg = 0; reg < 4; ++reg) {
        const size_t ro = (size_t)(rbase + reg) * 64;
        O[ro + c15]      = f2bf(acc0[reg] + bi0);
        O[ro + 16 + c15] = f2bf(acc1[reg] + bi1);
        O[ro + 32 + c15] = f2bf(acc2[reg] + bi2);
        O[ro + 48 + c15] = f2bf(acc3[reg] + bi3);
      }
    }
  }
}

// ======================= fused edge/attention kernel =======================
// One wave per dst node, block = 2 waves, no LDS in hot loop. Head-group
// reduce via DPP (quad_perm xor1/xor2 + row_ror:4/8) — pure VALU, no DS ops.
// exp2 with log2e folded into qv/tl. Packed KV dword, bf16 EA, 4-deep pipeline.
#define DPPRED(pl) do {                                                           \
    pl += __int_as_float(__builtin_amdgcn_update_dpp(0, __float_as_int(pl),       \
                                                     0xB1, 0xF, 0xF, true));      \
    pl += __int_as_float(__builtin_amdgcn_update_dpp(0, __float_as_int(pl),       \
                                                     0x4E, 0xF, 0xF, true));      \
    pl += __int_as_float(__builtin_amdgcn_update_dpp(0, __float_as_int(pl),       \
                                                     0x124, 0xF, 0xF, true));     \
    pl += __int_as_float(__builtin_amdgcn_update_dpp(0, __float_as_int(pl),       \
                                                     0x128, 0xF, 0xF, true));     \
  } while (0)

#define LOADST(KV, EE, jj) do {                                           \
    int jc_ = (jj) < mc ? (jj) : mc - 1;                                  \
    int off_ = __builtin_amdgcn_readlane(snv, jc_);                       \
    KV = *(const unsigned int*)(kvbase + off_);                           \
    EE = eabase[(size_t)(c0 + jc_) << 4];                                 \
  } while (0)

#define COMPUTE(KV, EE, jj) do {                                          \
    if ((jj) < mc) {                                                      \
      const float ef = bf2f(EE);                                          \
      const float kf = __uint_as_float(KV << 16);                         \
      const float vf = __uint_as_float(KV & 0xFFFF0000u);                 \
      float pl = qv * kf + tl * ef;                                       \
      DPPRED(pl);                                                         \
      const float p = exp2f(pl);                                          \
      ssum += p;                                                          \
      accv += p * vf;                                                     \
      accw += p * ef;                                                     \
    }                                                                     \
  } while (0)

__global__ __launch_bounds__(128, 8) void k_attn(
    const unsigned short* __restrict__ Qb, const unsigned short* __restrict__ KV16,
    const unsigned short* __restrict__ Tb, const unsigned short* __restrict__ Sb,
    const unsigned short* __restrict__ EAp,
    const int* __restrict__ esrcp, const int* __restrict__ rowptr,
    const float* __restrict__ We, const float* __restrict__ Wb,
    unsigned short* __restrict__ Hout, int n) {
  const int t = threadIdx.x;
  const int lane = t & 63;
  const int node = blockIdx.x * 2 + (t >> 6);
  if (node >= n) return;

  const float qv = bf2f(Qb[(size_t)node * 64 + lane]) * (SCALEF * LOG2E);
  const float tl = bf2f(Tb[(size_t)node * 64 + lane]) * LOG2E;
  const int r0 = rowptr[node], r1 = rowptr[node + 1];

  const char* kvbase = (const char*)KV16 + 4 * lane;
  const unsigned short* eabase = EAp + (lane & 15);

  float ssum = 0.f, accv = 0.f, accw = 0.f;

  for (int c0 = r0; c0 < r1; c0 += 64) {
    const int mc = min(64, r1 - c0);
    int snv = 0;
    if (lane < mc) snv = esrcp[c0 + lane];

    unsigned int kvA, kvB, kvC, kvD;
    unsigned short eA, eB, eC, eD;
    LOADST(kvA, eA, 0);
    LOADST(kvB, eB, 1);
    LOADST(kvC, eC, 2);
    LOADST(kvD, eD, 3);

    for (int j = 0; j < mc; j += 4) {
      COMPUTE(kvA, eA, j);     LOADST(kvA, eA, j + 4);
      COMPUTE(kvB, eB, j + 1); LOADST(kvB, eB, j + 5);
      COMPUTE(kvC, eC, j + 2); LOADST(kvC, eC, j + 6);
      COMPUTE(kvD, eD, j + 3); LOADST(kvD, eD, j + 7);
    }
  }

  float agg = accv;
  #pragma unroll
  for (int j = 0; j < 16; ++j) {
    const float wj = __shfl(accw, (lane & 48) | j, 64);
    agg += wj * We[j * 64 + lane];
  }
  agg /= (ssum + 1e-16f);

  const float sk = bf2f(Sb[(size_t)node * 64 + lane]);
  float contrib = agg * Wb[lane] + sk * Wb[64 + lane] + (agg - sk) * Wb[128 + lane];
  #pragma unroll
  for (int off = 1; off < 64; off <<= 1) contrib += __shfl_xor(contrib, off, 64);
  const float beta = 1.f / (1.f + __expf(-contrib));
  const float o = beta * sk + (1.f - beta) * agg;
  Hout[(size_t)node * 64 + lane] = f2bf(fmaxf(o, 0.f));
}

// ======================= fused pooling + MLP (one block per graph) =======================
__global__ __launch_bounds__(256) void k_poolmlp(const unsigned short* __restrict__ Hf,
    const int* __restrict__ batch,
    const float* __restrict__ Wlin, const float* __restrict__ blin,
    const float* __restrict__ Wout, const float* __restrict__ bout,
    float* __restrict__ out, int n) {
  const int g = blockIdx.x;
  const int t = threadIdx.x;
  const int lane = t & 63;
  const int w = t >> 6;

  int a = 0, b = n;
  while (a < b) { int mid = (a + b) >> 1; if (batch[mid] < g) a = mid + 1; else b = mid; }
  const int lo = a;
  b = n;
  while (a < b) { int mid = (a + b) >> 1; if (batch[mid] < g + 1) a = mid + 1; else b = mid; }
  const int hi = a;

  float vmax = -1e30f, vsum = 0.f;
  for (int i = lo + w; i < hi; i += 4) {
    const float v = bf2f(Hf[(size_t)i * 64 + lane]);
    vmax = fmaxf(vmax, v);
    vsum += v;
  }
  __shared__ float smax[4][64], ssum[4][64];
  __shared__ float cat[128];
  smax[w][lane] = vmax;
  ssum[w][lane] = vsum;
  __syncthreads();
  if (w == 0) {
    const float mx = fmaxf(fmaxf(smax[0][lane], smax[1][lane]),
                           fmaxf(smax[2][lane], smax[3][lane]));
    const float sm = ssum[0][lane] + ssum[1][lane] + ssum[2][lane] + ssum[3][lane];
    const int cnt = hi - lo;
    cat[lane]      = (cnt > 0) ? mx : 0.f;
    cat[64 + lane] = sm / fmaxf((float)cnt, 1.f);
  }
  __syncthreads();

  float acc = blin[t];
  for (int j = 0; j < 128; ++j) acc += cat[j] * Wlin[j * 256 + t];
  float p = acc * Wout[t];
  #pragma unroll
  for (int off = 1; off < 64; off <<= 1) p += __shfl_xor(p, off, 64);
  __shared__ float red[4];
  if ((t & 63) == 0) red[t >> 6] = p;
  __syncthreads();
  if (t == 0) {
    const float z = red[0] + red[1] + red[2] + red[3] + bout[0];
    out[g] = 1.f / (1.f + __expf(-z));
  }
}

// ======================= launcher =======================
extern "C" void kernel_launch(void* const* d_in, const int* in_sizes, int n_in,
                              void* d_out, int out_size, void* d_ws, size_t ws_size,
                              hipStream_t stream) {
  const float* x     = (const float*)d_in[0];
  const float* ea    = (const float*)d_in[1];
  const int*   eidx  = (const int*)d_in[2];
  const int*   batch = (const int*)d_in[3];
  const float *Wq0 = (const float*)d_in[4],  *bq0 = (const float*)d_in[5];
  const float *Wk0 = (const float*)d_in[6],  *bk0 = (const float*)d_in[7];
  const float *Wv0 = (const float*)d_in[8],  *bv0 = (const float*)d_in[9];
  const float *We0 = (const float*)d_in[10];
  const float *Ws0 = (const float*)d_in[11], *bs0 = (const float*)d_in[12];
  const float *Wb0 = (const float*)d_in[13];
  const float *Wq  = (const float*)d_in[14], *bq  = (const float*)d_in[15];
  const float *Wk  = (const float*)d_in[16], *bk  = (const float*)d_in[17];
  const float *Wv  = (const float*)d_in[18], *bv  = (const float*)d_in[19];
  const float *We  = (const float*)d_in[20];
  const float *Ws  = (const float*)d_in[21], *bs  = (const float*)d_in[22];
  const float *Wb  = (const float*)d_in[23];
  const float *Wlin = (const float*)d_in[24], *blin = (const float*)d_in[25];
  const float *Wout = (const float*)d_in[26], *bout = (const float*)d_in[27];

  const int N = in_sizes[0] / 64;
  const int E = in_sizes[2] / 2;
  const int G = out_size;
  const int* esrc = eidx;
  const int* edst = eidx + E;

  // ---- workspace carve ----
  char* wsp = (char*)d_ws;
  auto alloc = [&](size_t bytes) -> void* {
    void* p = (void*)wsp;
    wsp += (bytes + 255) & ~(size_t)255;
    return p;
  };
  unsigned short* Qb = (unsigned short*)alloc((size_t)N * 64 * 2);
  unsigned short* KV16 = (unsigned short*)alloc((size_t)N * 64 * 4);   // packed K|V
  unsigned short* Tb = (unsigned short*)alloc((size_t)N * 64 * 2);
  unsigned short* Sb16 = (unsigned short*)alloc((size_t)N * 64 * 2);
  unsigned short* Hb16 = (unsigned short*)alloc((size_t)N * 64 * 2);
  unsigned short* Xb16 = (unsigned short*)alloc((size_t)N * 64 * 2);
  int* counts  = (int*)alloc((size_t)N * 4);
  int* rowptr  = (int*)alloc((size_t)(N + 1) * 4);
  int* cursor  = (int*)alloc((size_t)N * 4);
  int* esrcp   = (int*)alloc((size_t)E * 4);
  unsigned short* EAp = (unsigned short*)alloc((size_t)E * 16 * 2);
  float* Wqt   = (float*)alloc(4 * 4096 * 4);
  float* bqt   = (float*)alloc(4 * 64 * 4);
  unsigned short* WT = (unsigned short*)alloc(4 * 5 * 4096 * 2);
  float* bcat  = (float*)alloc(4 * 5 * 64 * 4);

  // ---- CSR build + weight prep ----
  const int gridE = (E + 255) / 256;
  hipMemsetAsync(counts, 0, (size_t)N * 4, stream);
  k_hist<<<gridE, 256, 0, stream>>>(edst, counts, E);
  k_scanone<<<1, 1024, 0, stream>>>(counts, rowptr, cursor, N, E);
  k_scatperm<<<gridE, 256, 0, stream>>>(esrc, edst, ea, cursor, esrcp, EAp, E);
  k_wqt<<<4, 256, 0, stream>>>(Wq0, bq0, We0, Wq, bq, We, Wqt, bqt);
  k_prep<<<(N * 16 + 255) / 256, 256, 0, stream>>>(
      x, Xb16, N * 16,
      Wq0, Wk0, Wv0, Ws0, Wq, Wk, Wv, Ws, Wqt,
      bq0, bk0, bv0, bs0, bq, bk, bv, bs, bqt, WT, bcat);

  // ---- 4 TransformerConv layers ----
  const int gridLinM = ((N >> 4) + 3) / 4;
  const int gridAttn = (N + 1) / 2;
  for (int l = 0; l < 4; ++l) {
    const float* we_ = (l == 0) ? We0 : We + (l - 1) * 1024;
    const float* wb_ = (l == 0) ? Wb0 : Wb + (l - 1) * 192;
    const unsigned short* xin = (l == 0) ? Xb16 : Hb16;
    k_linm<<<gridLinM, 256, 0, stream>>>(xin, WT + (size_t)l * 20480, bcat + l * 320,
                                         Qb, KV16, Sb16, Tb, N);
    k_attn<<<gridAttn, 128, 0, stream>>>(Qb, KV16, Tb, Sb16, EAp, esrcp, rowptr,
                                         we_, wb_, Hb16, N);
  }

  // ---- fused pooling + MLP ----
  k_poolmlp<<<G, 256, 0, stream>>>(Hb16, batch, Wlin, blin, Wout, bout,
                                   (float*)d_out, N);
}

// Round 13
// 358.946 us; speedup vs baseline: 1.3257x; 1.3257x over previous
//
#include <hip/hip_runtime.h>
#include <math.h>

#define SCALEF 0.25f            // 1/sqrt(D=16)
#define LOG2E  1.4426950408889634f

typedef __attribute__((ext_vector_type(8))) short short8;
typedef __attribute__((ext_vector_type(4))) float f32x4;

__device__ __forceinline__ unsigned short f2bf(float x) {
  unsigned u = __float_as_uint(x);
  unsigned r = u + 0x7FFFu + ((u >> 16) & 1u);
  return (unsigned short)(r >> 16);
}
__device__ __forceinline__ float bf2f(unsigned short h) {
  return __uint_as_float(((unsigned)h) << 16);
}

// ======================= CSR build =======================
__global__ void k_hist(const int* __restrict__ dst, int* __restrict__ counts, int E) {
  int i = blockIdx.x * 256 + threadIdx.x;
  if (i < E) atomicAdd(&counts[dst[i]], 1);
}

__global__ __launch_bounds__(1024) void k_scan1(const int* __restrict__ counts,
                                                int* __restrict__ excl,
                                                int* __restrict__ bsums, int n) {
  __shared__ int sd[1024];
  int t = threadIdx.x;
  int i = blockIdx.x * 1024 + t;
  int v = (i < n) ? counts[i] : 0;
  sd[t] = v;
  __syncthreads();
  for (int off = 1; off < 1024; off <<= 1) {
    int x = (t >= off) ? sd[t - off] : 0;
    __syncthreads();
    sd[t] += x;
    __syncthreads();
  }
  if (i < n) excl[i] = sd[t] - v;
  if (t == 1023) bsums[blockIdx.x] = sd[1023];
}

// parallel wave-scan over <=64 block sums
__global__ __launch_bounds__(64) void k_scan2(int* bsums, int nb) {
  const int lane = threadIdx.x;
  int v = (lane < nb) ? bsums[lane] : 0;
  const int orig = v;
  for (int off = 1; off < 64; off <<= 1) {
    int u = __shfl_up(v, off, 64);
    if (lane >= off) v += u;
  }
  if (lane < nb) bsums[lane] = v - orig;   // exclusive
}

__global__ __launch_bounds__(1024) void k_scan3(int* __restrict__ rowptr, int* __restrict__ cursor,
                                                const int* __restrict__ bsums, int n, int Etot) {
  int i = blockIdx.x * 1024 + threadIdx.x;
  if (i < n) { int v = rowptr[i] + bsums[blockIdx.x]; rowptr[i] = v; cursor[i] = v; }
  if (i == 0) rowptr[n] = Etot;
}

// fused scatter+permute: place each edge directly at its CSR slot.
// esrcp holds BYTE offsets into the packed KV array (sn*256); EA -> bf16 row.
__global__ void k_scatperm(const int* __restrict__ esrc, const int* __restrict__ edst,
                           const float* __restrict__ EA, int* __restrict__ cursor,
                           int* __restrict__ esrcp, unsigned short* __restrict__ EAp, int E) {
  int i = blockIdx.x * 256 + threadIdx.x;
  if (i >= E) return;
  const int pos = atomicAdd(&cursor[edst[i]], 1);
  esrcp[pos] = esrc[i] * 256;
  const float4* s4 = (const float4*)(EA + ((size_t)i << 4));
  float4 a = s4[0], b = s4[1], c = s4[2], d = s4[3];
  union { unsigned short us[16]; uint4 u4[2]; } o;
  o.us[0] = f2bf(a.x); o.us[1] = f2bf(a.y); o.us[2] = f2bf(a.z); o.us[3] = f2bf(a.w);
  o.us[4] = f2bf(b.x); o.us[5] = f2bf(b.y); o.us[6] = f2bf(b.z); o.us[7] = f2bf(b.w);
  o.us[8] = f2bf(c.x); o.us[9] = f2bf(c.y); o.us[10] = f2bf(c.z); o.us[11] = f2bf(c.w);
  o.us[12] = f2bf(d.x); o.us[13] = f2bf(d.y); o.us[14] = f2bf(d.z); o.us[15] = f2bf(d.w);
  uint4* d4 = (uint4*)(EAp + ((size_t)pos << 4));
  d4[0] = o.u4[0]; d4[1] = o.u4[1];
}

// ======================= per-layer Wqt = (Wq @ M)*SCALE =======================
__global__ __launch_bounds__(256) void k_wqt(
    const float* __restrict__ Wq0, const float* __restrict__ bq0, const float* __restrict__ We0,
    const float* __restrict__ Wq, const float* __restrict__ bq, const float* __restrict__ We,
    float* __restrict__ Wqt, float* __restrict__ bqt) {
  const int l = blockIdx.x;
  const float* wq = (l == 0) ? Wq0 : Wq + (l - 1) * 4096;
  const float* bv = (l == 0) ? bq0 : bq + (l - 1) * 64;
  const float* we = (l == 0) ? We0 : We + (l - 1) * 1024;
  float* out  = Wqt + l * 4096;
  float* outb = bqt + l * 64;
  const int t = threadIdx.x;
  const int r = t >> 2;
  const int hh = t & 3;
  float wqr[16];
  #pragma unroll
  for (int d = 0; d < 16; ++d) wqr[d] = wq[r * 64 + hh * 16 + d];
  #pragma unroll
  for (int bb = 0; bb < 16; ++bb) {
    float s = 0.f;
    #pragma unroll
    for (int d = 0; d < 16; ++d) s += wqr[d] * we[bb * 64 + hh * 16 + d];
    out[r * 64 + hh * 16 + bb] = s * SCALEF;
  }
  if (r == 0) {
    #pragma unroll
    for (int bb = 0; bb < 16; ++bb) {
      float s = 0.f;
      #pragma unroll
      for (int d = 0; d < 16; ++d) s += bv[hh * 16 + d] * we[bb * 64 + hh * 16 + d];
      outb[hh * 16 + bb] = s * SCALEF;
    }
  }
}

// ======================= fused prep: weight transpose->bf16 + x->bf16 =======================
__global__ void k_prep(
    const float* __restrict__ x, unsigned short* __restrict__ xb, int n16,
    const float* __restrict__ Wq0, const float* __restrict__ Wk0, const float* __restrict__ Wv0,
    const float* __restrict__ Ws0,
    const float* __restrict__ Wq, const float* __restrict__ Wk, const float* __restrict__ Wv,
    const float* __restrict__ Ws, const float* __restrict__ Wqt,
    const float* __restrict__ bq0, const float* __restrict__ bk0, const float* __restrict__ bv0,
    const float* __restrict__ bs0,
    const float* __restrict__ bq, const float* __restrict__ bk, const float* __restrict__ bv,
    const float* __restrict__ bs, const float* __restrict__ bqt,
    unsigned short* __restrict__ WT, float* __restrict__ bcat) {
  const int id = blockIdx.x * 256 + threadIdx.x;
  if (id < n16) {
    float4 v = ((const float4*)x)[id];
    ushort4 o;
    o.x = f2bf(v.x); o.y = f2bf(v.y); o.z = f2bf(v.z); o.w = f2bf(v.w);
    ((ushort4*)xb)[id] = o;
  }
  if (id < 4 * 5 * 4096) {
    const int l = id / 20480;
    const int rem = id - l * 20480;
    const int mat = rem >> 12;
    const int idx = rem & 4095;
    const int k = idx >> 6;
    const int c = idx & 63;
    float v;
    if (mat == 0)      v = (l == 0) ? Wq0[idx] : Wq[(l - 1) * 4096 + idx];
    else if (mat == 1) v = (l == 0) ? Wk0[idx] : Wk[(l - 1) * 4096 + idx];
    else if (mat == 2) v = (l == 0) ? Wv0[idx] : Wv[(l - 1) * 4096 + idx];
    else if (mat == 3) v = (l == 0) ? Ws0[idx] : Ws[(l - 1) * 4096 + idx];
    else               v = Wqt[l * 4096 + idx];
    WT[(size_t)(l * 5 + mat) * 4096 + c * 64 + k] = f2bf(v);
    if (k == 0) {
      float b;
      if (mat == 0)      b = (l == 0) ? bq0[c] : bq[(l - 1) * 64 + c];
      else if (mat == 1) b = (l == 0) ? bk0[c] : bk[(l - 1) * 64 + c];
      else if (mat == 2) b = (l == 0) ? bv0[c] : bv[(l - 1) * 64 + c];
      else if (mat == 3) b = (l == 0) ? bs0[c] : bs[(l - 1) * 64 + c];
      else               b = bqt[l * 64 + c];
      bcat[(l * 5 + mat) * 64 + c] = b;
    }
  }
}

// ======================= node linear via MFMA =======================
// One wave per 16-row tile; all 5 matrices (40 MFMA) reuse the A fragments.
// K,V write interleaved into KV16 (uint per (node,col): K low / V high ushort).
__global__ __launch_bounds__(256) void k_linm(
    const unsigned short* __restrict__ Xb, const unsigned short* __restrict__ WT,
    const float* __restrict__ bcat,
    unsigned short* __restrict__ Qb, unsigned short* __restrict__ KV16,
    unsigned short* __restrict__ Sb, unsigned short* __restrict__ Tb, int n) {
  const int lane = threadIdx.x & 63;
  const int tile = blockIdx.x * 4 + (threadIdx.x >> 6);
  const int ntr = n >> 4;                    // N % 16 == 0
  if (tile >= ntr) return;
  const int r0 = tile << 4;
  const int c15 = lane & 15;
  const int kg = lane >> 4;                  // 0..3
  const int rbase = r0 + kg * 4;

  const unsigned short* xrow = Xb + (size_t)(r0 + c15) * 64 + kg * 8;
  const short8 a0 = *(const short8*)(xrow);
  const short8 a1 = *(const short8*)(xrow + 32);

  #pragma unroll
  for (int mat = 0; mat < 5; ++mat) {
    const unsigned short* wb = WT + ((size_t)mat << 12) + (size_t)c15 * 64 + kg * 8;
    f32x4 acc0 = {0.f, 0.f, 0.f, 0.f}, acc1 = acc0, acc2 = acc0, acc3 = acc0;
    {
      short8 b0 = *(const short8*)(wb);
      short8 b1 = *(const short8*)(wb + 32);
      acc0 = __builtin_amdgcn_mfma_f32_16x16x32_bf16(a0, b0, acc0, 0, 0, 0);
      acc0 = __builtin_amdgcn_mfma_f32_16x16x32_bf16(a1, b1, acc0, 0, 0, 0);
    }
    {
      short8 b0 = *(const short8*)(wb + 16 * 64);
      short8 b1 = *(const short8*)(wb + 16 * 64 + 32);
      acc1 = __builtin_amdgcn_mfma_f32_16x16x32_bf16(a0, b0, acc1, 0, 0, 0);
      acc1 = __builtin_amdgcn_mfma_f32_16x16x32_bf16(a1, b1, acc1, 0, 0, 0);
    }
    {
      short8 b0 = *(const short8*)(wb + 32 * 64);
      short8 b1 = *(const short8*)(wb + 32 * 64 + 32);
      acc2 = __builtin_amdgcn_mfma_f32_16x16x32_bf16(a0, b0, acc2, 0, 0, 0);
      acc2 = __builtin_amdgcn_mfma_f32_16x16x32_bf16(a1, b1, acc2, 0, 0, 0);
    }
    {
      short8 b0 = *(const short8*)(wb + 48 * 64);
      short8 b1 = *(const short8*)(wb + 48 * 64 + 32);
      acc3 = __builtin_amdgcn_mfma_f32_16x16x32_bf16(a0, b0, acc3, 0, 0, 0);
      acc3 = __builtin_amdgcn_mfma_f32_16x16x32_bf16(a1, b1, acc3, 0, 0, 0);
    }

    const float* bb = bcat + mat * 64;
    const float bi0 = bb[c15], bi1 = bb[16 + c15], bi2 = bb[32 + c15], bi3 = bb[48 + c15];

    if (mat == 1 || mat == 2) {
      unsigned short* O = KV16 + (mat == 2 ? 1 : 0);
      #pragma unroll
      for (int reg = 0; reg < 4; ++reg) {
        const size_t ro = (size_t)(rbase + reg) * 128;
        O[ro + 2 * c15]        = f2bf(acc0[reg] + bi0);
        O[ro + 2 * (16 + c15)] = f2bf(acc1[reg] + bi1);
        O[ro + 2 * (32 + c15)] = f2bf(acc2[reg] + bi2);
        O[ro + 2 * (48 + c15)] = f2bf(acc3[reg] + bi3);
      }
    } else {
      unsigned short* O = (mat == 0) ? Qb : (mat == 3) ? Sb : Tb;
      #pragma unroll
      for (int reg = 0; reg < 4; ++reg) {
        const size_t ro = (size_t)(rbase + reg) * 64;
        O[ro + c15]      = f2bf(acc0[reg] + bi0);
        O[ro + 16 + c15] = f2bf(acc1[reg] + bi1);
        O[ro + 32 + c15] = f2bf(acc2[reg] + bi2);
        O[ro + 48 + c15] = f2bf(acc3[reg] + bi3);
      }
    }
  }
}

// ======================= fused edge/attention kernel =======================
// One wave per dst node, block = 2 waves, no LDS in hot loop. Head-group
// reduce via DPP (quad_perm xor1/xor2 + row_ror:4/8) — pure VALU, no DS ops.
// exp2 with log2e folded into qv/tl. Packed KV dword, bf16 EA, 4-deep pipeline.
#define DPPRED(pl) do {                                                           \
    pl += __int_as_float(__builtin_amdgcn_update_dpp(0, __float_as_int(pl),       \
                                                     0xB1, 0xF, 0xF, true));      \
    pl += __int_as_float(__builtin_amdgcn_update_dpp(0, __float_as_int(pl),       \
                                                     0x4E, 0xF, 0xF, true));      \
    pl += __int_as_float(__builtin_amdgcn_update_dpp(0, __float_as_int(pl),       \
                                                     0x124, 0xF, 0xF, true));     \
    pl += __int_as_float(__builtin_amdgcn_update_dpp(0, __float_as_int(pl),       \
                                                     0x128, 0xF, 0xF, true));     \
  } while (0)

#define LOADST(KV, EE, jj) do {                                           \
    int jc_ = (jj) < mc ? (jj) : mc - 1;                                  \
    int off_ = __builtin_amdgcn_readlane(snv, jc_);                       \
    KV = *(const unsigned int*)(kvbase + off_);                           \
    EE = eabase[(size_t)(c0 + jc_) << 4];                                 \
  } while (0)

#define COMPUTE(KV, EE, jj) do {                                          \
    if ((jj) < mc) {                                                      \
      const float ef = bf2f(EE);                                          \
      const float kf = __uint_as_float(KV << 16);                         \
      const float vf = __uint_as_float(KV & 0xFFFF0000u);                 \
      float pl = qv * kf + tl * ef;                                       \
      DPPRED(pl);                                                         \
      const float p = exp2f(pl);                                          \
      ssum += p;                                                          \
      accv += p * vf;                                                     \
      accw += p * ef;                                                     \
    }                                                                     \
  } while (0)

__global__ __launch_bounds__(128, 8) void k_attn(
    const unsigned short* __restrict__ Qb, const unsigned short* __restrict__ KV16,
    const unsigned short* __restrict__ Tb, const unsigned short* __restrict__ Sb,
    const unsigned short* __restrict__ EAp,
    const int* __restrict__ esrcp, const int* __restrict__ rowptr,
    const float* __restrict__ We, const float* __restrict__ Wb,
    unsigned short* __restrict__ Hout, int n) {
  const int t = threadIdx.x;
  const int lane = t & 63;
  const int node = blockIdx.x * 2 + (t >> 6);
  if (node >= n) return;

  const float qv = bf2f(Qb[(size_t)node * 64 + lane]) * (SCALEF * LOG2E);
  const float tl = bf2f(Tb[(size_t)node * 64 + lane]) * LOG2E;
  const int r0 = rowptr[node], r1 = rowptr[node + 1];

  const char* kvbase = (const char*)KV16 + 4 * lane;
  const unsigned short* eabase = EAp + (lane & 15);

  float ssum = 0.f, accv = 0.f, accw = 0.f;

  for (int c0 = r0; c0 < r1; c0 += 64) {
    const int mc = min(64, r1 - c0);
    int snv = 0;
    if (lane < mc) snv = esrcp[c0 + lane];

    unsigned int kvA, kvB, kvC, kvD;
    unsigned short eA, eB, eC, eD;
    LOADST(kvA, eA, 0);
    LOADST(kvB, eB, 1);
    LOADST(kvC, eC, 2);
    LOADST(kvD, eD, 3);

    for (int j = 0; j < mc; j += 4) {
      COMPUTE(kvA, eA, j);     LOADST(kvA, eA, j + 4);
      COMPUTE(kvB, eB, j + 1); LOADST(kvB, eB, j + 5);
      COMPUTE(kvC, eC, j + 2); LOADST(kvC, eC, j + 6);
      COMPUTE(kvD, eD, j + 3); LOADST(kvD, eD, j + 7);
    }
  }

  float agg = accv;
  #pragma unroll
  for (int j = 0; j < 16; ++j) {
    const float wj = __shfl(accw, (lane & 48) | j, 64);
    agg += wj * We[j * 64 + lane];
  }
  agg /= (ssum + 1e-16f);

  const float sk = bf2f(Sb[(size_t)node * 64 + lane]);
  float contrib = agg * Wb[lane] + sk * Wb[64 + lane] + (agg - sk) * Wb[128 + lane];
  #pragma unroll
  for (int off = 1; off < 64; off <<= 1) contrib += __shfl_xor(contrib, off, 64);
  const float beta = 1.f / (1.f + __expf(-contrib));
  const float o = beta * sk + (1.f - beta) * agg;
  Hout[(size_t)node * 64 + lane] = f2bf(fmaxf(o, 0.f));
}

// ======================= fused pooling + MLP (one block per graph) =======================
__global__ __launch_bounds__(256) void k_poolmlp(const unsigned short* __restrict__ Hf,
    const int* __restrict__ batch,
    const float* __restrict__ Wlin, const float* __restrict__ blin,
    const float* __restrict__ Wout, const float* __restrict__ bout,
    float* __restrict__ out, int n) {
  const int g = blockIdx.x;
  const int t = threadIdx.x;
  const int lane = t & 63;
  const int w = t >> 6;

  int a = 0, b = n;
  while (a < b) { int mid = (a + b) >> 1; if (batch[mid] < g) a = mid + 1; else b = mid; }
  const int lo = a;
  b = n;
  while (a < b) { int mid = (a + b) >> 1; if (batch[mid] < g + 1) a = mid + 1; else b = mid; }
  const int hi = a;

  float vmax = -1e30f, vsum = 0.f;
  for (int i = lo + w; i < hi; i += 4) {
    const float v = bf2f(Hf[(size_t)i * 64 + lane]);
    vmax = fmaxf(vmax, v);
    vsum += v;
  }
  __shared__ float smax[4][64], ssum[4][64];
  __shared__ float cat[128];
  smax[w][lane] = vmax;
  ssum[w][lane] = vsum;
  __syncthreads();
  if (w == 0) {
    const float mx = fmaxf(fmaxf(smax[0][lane], smax[1][lane]),
                           fmaxf(smax[2][lane], smax[3][lane]));
    const float sm = ssum[0][lane] + ssum[1][lane] + ssum[2][lane] + ssum[3][lane];
    const int cnt = hi - lo;
    cat[lane]      = (cnt > 0) ? mx : 0.f;
    cat[64 + lane] = sm / fmaxf((float)cnt, 1.f);
  }
  __syncthreads();

  float acc = blin[t];
  for (int j = 0; j < 128; ++j) acc += cat[j] * Wlin[j * 256 + t];
  float p = acc * Wout[t];
  #pragma unroll
  for (int off = 1; off < 64; off <<= 1) p += __shfl_xor(p, off, 64);
  __shared__ float red[4];
  if ((t & 63) == 0) red[t >> 6] = p;
  __syncthreads();
  if (t == 0) {
    const float z = red[0] + red[1] + red[2] + red[3] + bout[0];
    out[g] = 1.f / (1.f + __expf(-z));
  }
}

// ======================= launcher =======================
extern "C" void kernel_launch(void* const* d_in, const int* in_sizes, int n_in,
                              void* d_out, int out_size, void* d_ws, size_t ws_size,
                              hipStream_t stream) {
  const float* x     = (const float*)d_in[0];
  const float* ea    = (const float*)d_in[1];
  const int*   eidx  = (const int*)d_in[2];
  const int*   batch = (const int*)d_in[3];
  const float *Wq0 = (const float*)d_in[4],  *bq0 = (const float*)d_in[5];
  const float *Wk0 = (const float*)d_in[6],  *bk0 = (const float*)d_in[7];
  const float *Wv0 = (const float*)d_in[8],  *bv0 = (const float*)d_in[9];
  const float *We0 = (const float*)d_in[10];
  const float *Ws0 = (const float*)d_in[11], *bs0 = (const float*)d_in[12];
  const float *Wb0 = (const float*)d_in[13];
  const float *Wq  = (const float*)d_in[14], *bq  = (const float*)d_in[15];
  const float *Wk  = (const float*)d_in[16], *bk  = (const float*)d_in[17];
  const float *Wv  = (const float*)d_in[18], *bv  = (const float*)d_in[19];
  const float *We  = (const float*)d_in[20];
  const float *Ws  = (const float*)d_in[21], *bs  = (const float*)d_in[22];
  const float *Wb  = (const float*)d_in[23];
  const float *Wlin = (const float*)d_in[24], *blin = (const float*)d_in[25];
  const float *Wout = (const float*)d_in[26], *bout = (const float*)d_in[27];

  const int N = in_sizes[0] / 64;
  const int E = in_sizes[2] / 2;
  const int G = out_size;
  const int* esrc = eidx;
  const int* edst = eidx + E;

  // ---- workspace carve ----
  char* wsp = (char*)d_ws;
  auto alloc = [&](size_t bytes) -> void* {
    void* p = (void*)wsp;
    wsp += (bytes + 255) & ~(size_t)255;
    return p;
  };
  unsigned short* Qb = (unsigned short*)alloc((size_t)N * 64 * 2);
  unsigned short* KV16 = (unsigned short*)alloc((size_t)N * 64 * 4);   // packed K|V
  unsigned short* Tb = (unsigned short*)alloc((size_t)N * 64 * 2);
  unsigned short* Sb16 = (unsigned short*)alloc((size_t)N * 64 * 2);
  unsigned short* Hb16 = (unsigned short*)alloc((size_t)N * 64 * 2);
  unsigned short* Xb16 = (unsigned short*)alloc((size_t)N * 64 * 2);
  int* counts  = (int*)alloc((size_t)N * 4);
  int* rowptr  = (int*)alloc((size_t)(N + 1) * 4);
  int* cursor  = (int*)alloc((size_t)N * 4);
  int* bsums   = (int*)alloc(1024 * 4);
  int* esrcp   = (int*)alloc((size_t)E * 4);
  unsigned short* EAp = (unsigned short*)alloc((size_t)E * 16 * 2);
  float* Wqt   = (float*)alloc(4 * 4096 * 4);
  float* bqt   = (float*)alloc(4 * 64 * 4);
  unsigned short* WT = (unsigned short*)alloc(4 * 5 * 4096 * 2);
  float* bcat  = (float*)alloc(4 * 5 * 64 * 4);

  // ---- CSR build + weight prep ----
  const int gridE = (E + 255) / 256;
  const int NB1 = (N + 1023) / 1024;
  hipMemsetAsync(counts, 0, (size_t)N * 4, stream);
  k_hist<<<gridE, 256, 0, stream>>>(edst, counts, E);
  k_scan1<<<NB1, 1024, 0, stream>>>(counts, rowptr, bsums, N);
  k_scan2<<<1, 64, 0, stream>>>(bsums, NB1);
  k_scan3<<<NB1, 1024, 0, stream>>>(rowptr, cursor, bsums, N, E);
  k_scatperm<<<gridE, 256, 0, stream>>>(esrc, edst, ea, cursor, esrcp, EAp, E);
  k_wqt<<<4, 256, 0, stream>>>(Wq0, bq0, We0, Wq, bq, We, Wqt, bqt);
  k_prep<<<(N * 16 + 255) / 256, 256, 0, stream>>>(
      x, Xb16, N * 16,
      Wq0, Wk0, Wv0, Ws0, Wq, Wk, Wv, Ws, Wqt,
      bq0, bk0, bv0, bs0, bq, bk, bv, bs, bqt, WT, bcat);

  // ---- 4 TransformerConv layers ----
  const int gridLinM = ((N >> 4) + 3) / 4;
  const int gridAttn = (N + 1) / 2;
  for (int l = 0; l < 4; ++l) {
    const float* we_ = (l == 0) ? We0 : We + (l - 1) * 1024;
    const float* wb_ = (l == 0) ? Wb0 : Wb + (l - 1) * 192;
    const unsigned short* xin = (l == 0) ? Xb16 : Hb16;
    k_linm<<<gridLinM, 256, 0, stream>>>(xin, WT + (size_t)l * 20480, bcat + l * 320,
                                         Qb, KV16, Sb16, Tb, N);
    k_attn<<<gridAttn, 128, 0, stream>>>(Qb, KV16, Tb, Sb16, EAp, esrcp, rowptr,
                                         we_, wb_, Hb16, N);
  }

  // ---- fused pooling + MLP ----
  k_poolmlp<<<G, 256, 0, stream>>>(Hb16, batch, Wlin, blin, Wout, bout,
                                   (float*)d_out, N);
}

// Round 14
// 355.624 us; speedup vs baseline: 1.3381x; 1.0093x over previous
//
#include <hip/hip_runtime.h>
#include <math.h>

#define SCALEF 0.25f            // 1/sqrt(D=16)
#define LOG2E  1.4426950408889634f

typedef __attribute__((ext_vector_type(8))) short short8;
typedef __attribute__((ext_vector_type(4))) float f32x4;

__device__ __forceinline__ unsigned short f2bf(float x) {
  unsigned u = __float_as_uint(x);
  unsigned r = u + 0x7FFFu + ((u >> 16) & 1u);
  return (unsigned short)(r >> 16);
}
__device__ __forceinline__ float bf2f(unsigned short h) {
  return __uint_as_float(((unsigned)h) << 16);
}

// ======================= CSR build =======================
__global__ void k_hist(const int* __restrict__ dst, int* __restrict__ counts, int E) {
  int i = blockIdx.x * 256 + threadIdx.x;
  if (i < E) atomicAdd(&counts[dst[i]], 1);
}

__global__ __launch_bounds__(1024) void k_scan1(const int* __restrict__ counts,
                                                int* __restrict__ excl,
                                                int* __restrict__ bsums, int n) {
  __shared__ int sd[1024];
  int t = threadIdx.x;
  int i = blockIdx.x * 1024 + t;
  int v = (i < n) ? counts[i] : 0;
  sd[t] = v;
  __syncthreads();
  for (int off = 1; off < 1024; off <<= 1) {
    int x = (t >= off) ? sd[t - off] : 0;
    __syncthreads();
    sd[t] += x;
    __syncthreads();
  }
  if (i < n) excl[i] = sd[t] - v;
  if (t == 1023) bsums[blockIdx.x] = sd[1023];
}

// parallel wave-scan over <=64 block sums
__global__ __launch_bounds__(64) void k_scan2(int* bsums, int nb) {
  const int lane = threadIdx.x;
  int v = (lane < nb) ? bsums[lane] : 0;
  const int orig = v;
  for (int off = 1; off < 64; off <<= 1) {
    int u = __shfl_up(v, off, 64);
    if (lane >= off) v += u;
  }
  if (lane < nb) bsums[lane] = v - orig;   // exclusive
}

__global__ __launch_bounds__(1024) void k_scan3(int* __restrict__ rowptr, int* __restrict__ cursor,
                                                const int* __restrict__ bsums, int n, int Etot) {
  int i = blockIdx.x * 1024 + threadIdx.x;
  if (i < n) { int v = rowptr[i] + bsums[blockIdx.x]; rowptr[i] = v; cursor[i] = v; }
  if (i == 0) rowptr[n] = Etot;
}

// fused scatter+permute: place each edge directly at its CSR slot.
// esrcp holds BYTE offsets into the packed KV array (sn*256); EA -> bf16 row.
__global__ void k_scatperm(const int* __restrict__ esrc, const int* __restrict__ edst,
                           const float* __restrict__ EA, int* __restrict__ cursor,
                           int* __restrict__ esrcp, unsigned short* __restrict__ EAp, int E) {
  int i = blockIdx.x * 256 + threadIdx.x;
  if (i >= E) return;
  const int pos = atomicAdd(&cursor[edst[i]], 1);
  esrcp[pos] = esrc[i] * 256;
  const float4* s4 = (const float4*)(EA + ((size_t)i << 4));
  float4 a = s4[0], b = s4[1], c = s4[2], d = s4[3];
  union { unsigned short us[16]; uint4 u4[2]; } o;
  o.us[0] = f2bf(a.x); o.us[1] = f2bf(a.y); o.us[2] = f2bf(a.z); o.us[3] = f2bf(a.w);
  o.us[4] = f2bf(b.x); o.us[5] = f2bf(b.y); o.us[6] = f2bf(b.z); o.us[7] = f2bf(b.w);
  o.us[8] = f2bf(c.x); o.us[9] = f2bf(c.y); o.us[10] = f2bf(c.z); o.us[11] = f2bf(c.w);
  o.us[12] = f2bf(d.x); o.us[13] = f2bf(d.y); o.us[14] = f2bf(d.z); o.us[15] = f2bf(d.w);
  uint4* d4 = (uint4*)(EAp + ((size_t)pos << 4));
  d4[0] = o.u4[0]; d4[1] = o.u4[1];
}

// ======================= per-layer Wqt = (Wq @ M)*SCALE =======================
__global__ __launch_bounds__(256) void k_wqt(
    const float* __restrict__ Wq0, const float* __restrict__ bq0, const float* __restrict__ We0,
    const float* __restrict__ Wq, const float* __restrict__ bq, const float* __restrict__ We,
    float* __restrict__ Wqt, float* __restrict__ bqt) {
  const int l = blockIdx.x;
  const float* wq = (l == 0) ? Wq0 : Wq + (l - 1) * 4096;
  const float* bv = (l == 0) ? bq0 : bq + (l - 1) * 64;
  const float* we = (l == 0) ? We0 : We + (l - 1) * 1024;
  float* out  = Wqt + l * 4096;
  float* outb = bqt + l * 64;
  const int t = threadIdx.x;
  const int r = t >> 2;
  const int hh = t & 3;
  float wqr[16];
  #pragma unroll
  for (int d = 0; d < 16; ++d) wqr[d] = wq[r * 64 + hh * 16 + d];
  #pragma unroll
  for (int bb = 0; bb < 16; ++bb) {
    float s = 0.f;
    #pragma unroll
    for (int d = 0; d < 16; ++d) s += wqr[d] * we[bb * 64 + hh * 16 + d];
    out[r * 64 + hh * 16 + bb] = s * SCALEF;
  }
  if (r == 0) {
    #pragma unroll
    for (int bb = 0; bb < 16; ++bb) {
      float s = 0.f;
      #pragma unroll
      for (int d = 0; d < 16; ++d) s += bv[hh * 16 + d] * we[bb * 64 + hh * 16 + d];
      outb[hh * 16 + bb] = s * SCALEF;
    }
  }
}

// ======================= fused prep: weight transpose->bf16 + x->bf16 =======================
__global__ void k_prep(
    const float* __restrict__ x, unsigned short* __restrict__ xb, int n16,
    const float* __restrict__ Wq0, const float* __restrict__ Wk0, const float* __restrict__ Wv0,
    const float* __restrict__ Ws0,
    const float* __restrict__ Wq, const float* __restrict__ Wk, const float* __restrict__ Wv,
    const float* __restrict__ Ws, const float* __restrict__ Wqt,
    const float* __restrict__ bq0, const float* __restrict__ bk0, const float* __restrict__ bv0,
    const float* __restrict__ bs0,
    const float* __restrict__ bq, const float* __restrict__ bk, const float* __restrict__ bv,
    const float* __restrict__ bs, const float* __restrict__ bqt,
    unsigned short* __restrict__ WT, float* __restrict__ bcat) {
  const int id = blockIdx.x * 256 + threadIdx.x;
  if (id < n16) {
    float4 v = ((const float4*)x)[id];
    ushort4 o;
    o.x = f2bf(v.x); o.y = f2bf(v.y); o.z = f2bf(v.z); o.w = f2bf(v.w);
    ((ushort4*)xb)[id] = o;
  }
  if (id < 4 * 5 * 4096) {
    const int l = id / 20480;
    const int rem = id - l * 20480;
    const int mat = rem >> 12;
    const int idx = rem & 4095;
    const int k = idx >> 6;
    const int c = idx & 63;
    float v;
    if (mat == 0)      v = (l == 0) ? Wq0[idx] : Wq[(l - 1) * 4096 + idx];
    else if (mat == 1) v = (l == 0) ? Wk0[idx] : Wk[(l - 1) * 4096 + idx];
    else if (mat == 2) v = (l == 0) ? Wv0[idx] : Wv[(l - 1) * 4096 + idx];
    else if (mat == 3) v = (l == 0) ? Ws0[idx] : Ws[(l - 1) * 4096 + idx];
    else               v = Wqt[l * 4096 + idx];
    WT[(size_t)(l * 5 + mat) * 4096 + c * 64 + k] = f2bf(v);
    if (k == 0) {
      float b;
      if (mat == 0)      b = (l == 0) ? bq0[c] : bq[(l - 1) * 64 + c];
      else if (mat == 1) b = (l == 0) ? bk0[c] : bk[(l - 1) * 64 + c];
      else if (mat == 2) b = (l == 0) ? bv0[c] : bv[(l - 1) * 64 + c];
      else if (mat == 3) b = (l == 0) ? bs0[c] : bs[(l - 1) * 64 + c];
      else               b = bqt[l * 64 + c];
      bcat[(l * 5 + mat) * 64 + c] = b;
    }
  }
}

// ======================= node linear via MFMA =======================
// One wave per 16-row tile; all 5 matrices (40 MFMA) reuse the A fragments.
// Matrices processed in pairs sharing PACKED dword stores: (K,V)->KVu,
// (Q,T)->QTu, S alone as ushort. 48 stores/wave (was 80 scalar ushort).
__device__ __forceinline__ void mat_gemm(const unsigned short* __restrict__ wb,
                                         const short8 a0, const short8 a1,
                                         f32x4 acc[4]) {
  #pragma unroll
  for (int cf = 0; cf < 4; ++cf) {
    short8 b0 = *(const short8*)(wb + cf * 1024);
    short8 b1 = *(const short8*)(wb + cf * 1024 + 32);
    acc[cf] = __builtin_amdgcn_mfma_f32_16x16x32_bf16(a0, b0, acc[cf], 0, 0, 0);
    acc[cf] = __builtin_amdgcn_mfma_f32_16x16x32_bf16(a1, b1, acc[cf], 0, 0, 0);
  }
}

__global__ __launch_bounds__(256) void k_linm(
    const unsigned short* __restrict__ Xb, const unsigned short* __restrict__ WT,
    const float* __restrict__ bcat,
    unsigned int* __restrict__ QTu, unsigned int* __restrict__ KVu,
    unsigned short* __restrict__ Sb, int n) {
  const int lane = threadIdx.x & 63;
  const int tile = blockIdx.x * 4 + (threadIdx.x >> 6);
  const int ntr = n >> 4;                    // N % 16 == 0
  if (tile >= ntr) return;
  const int r0 = tile << 4;
  const int c15 = lane & 15;
  const int kg = lane >> 4;                  // 0..3
  const int rbase = r0 + kg * 4;

  const unsigned short* xrow = Xb + (size_t)(r0 + c15) * 64 + kg * 8;
  const short8 a0 = *(const short8*)(xrow);
  const short8 a1 = *(const short8*)(xrow + 32);
  const f32x4 z = {0.f, 0.f, 0.f, 0.f};

  // ---- pair (K=mat1, V=mat2) -> packed KVu ----
  {
    f32x4 aK[4] = {z, z, z, z}, aV[4] = {z, z, z, z};
    mat_gemm(WT + (1 << 12) + (size_t)c15 * 64 + kg * 8, a0, a1, aK);
    mat_gemm(WT + (2 << 12) + (size_t)c15 * 64 + kg * 8, a0, a1, aV);
    #pragma unroll
    for (int cf = 0; cf < 4; ++cf) {
      const float bk_ = bcat[1 * 64 + cf * 16 + c15];
      const float bv_ = bcat[2 * 64 + cf * 16 + c15];
      #pragma unroll
      for (int reg = 0; reg < 4; ++reg) {
        const unsigned pk = f2bf(aK[cf][reg] + bk_);
        const unsigned pv = f2bf(aV[cf][reg] + bv_);
        KVu[(size_t)(rbase + reg) * 64 + cf * 16 + c15] = pk | (pv << 16);
      }
    }
  }

  // ---- pair (Q=mat0, T=mat4) -> packed QTu ----
  {
    f32x4 aQ[4] = {z, z, z, z}, aT[4] = {z, z, z, z};
    mat_gemm(WT + (0 << 12) + (size_t)c15 * 64 + kg * 8, a0, a1, aQ);
    mat_gemm(WT + ((size_t)4 << 12) + (size_t)c15 * 64 + kg * 8, a0, a1, aT);
    #pragma unroll
    for (int cf = 0; cf < 4; ++cf) {
      const float bq_ = bcat[0 * 64 + cf * 16 + c15];
      const float bt_ = bcat[4 * 64 + cf * 16 + c15];
      #pragma unroll
      for (int reg = 0; reg < 4; ++reg) {
        const unsigned pq = f2bf(aQ[cf][reg] + bq_);
        const unsigned pt = f2bf(aT[cf][reg] + bt_);
        QTu[(size_t)(rbase + reg) * 64 + cf * 16 + c15] = pq | (pt << 16);
      }
    }
  }

  // ---- S = mat3 (ushort) ----
  {
    f32x4 aS[4] = {z, z, z, z};
    mat_gemm(WT + ((size_t)3 << 12) + (size_t)c15 * 64 + kg * 8, a0, a1, aS);
    #pragma unroll
    for (int cf = 0; cf < 4; ++cf) {
      const float bs_ = bcat[3 * 64 + cf * 16 + c15];
      #pragma unroll
      for (int reg = 0; reg < 4; ++reg) {
        Sb[(size_t)(rbase + reg) * 64 + cf * 16 + c15] = f2bf(aS[cf][reg] + bs_);
      }
    }
  }
}

// ======================= fused edge/attention kernel =======================
// One wave per dst node, block = 2 waves, no LDS in hot loop. Head-group
// reduce via DPP (quad_perm xor1/xor2 + row_ror:4/8) — pure VALU, no DS ops.
// exp2 with log2e folded into qv/tl. Packed KV + packed QT dwords.
#define DPPRED(pl) do {                                                           \
    pl += __int_as_float(__builtin_amdgcn_update_dpp(0, __float_as_int(pl),       \
                                                     0xB1, 0xF, 0xF, true));      \
    pl += __int_as_float(__builtin_amdgcn_update_dpp(0, __float_as_int(pl),       \
                                                     0x4E, 0xF, 0xF, true));      \
    pl += __int_as_float(__builtin_amdgcn_update_dpp(0, __float_as_int(pl),       \
                                                     0x124, 0xF, 0xF, true));     \
    pl += __int_as_float(__builtin_amdgcn_update_dpp(0, __float_as_int(pl),       \
                                                     0x128, 0xF, 0xF, true));     \
  } while (0)

#define LOADST(KV, EE, jj) do {                                           \
    int jc_ = (jj) < mc ? (jj) : mc - 1;                                  \
    int off_ = __builtin_amdgcn_readlane(snv, jc_);                       \
    KV = *(const unsigned int*)(kvbase + off_);                           \
    EE = eabase[(size_t)(c0 + jc_) << 4];                                 \
  } while (0)

#define COMPUTE(KV, EE, jj) do {                                          \
    if ((jj) < mc) {                                                      \
      const float ef = bf2f(EE);                                          \
      const float kf = __uint_as_float(KV << 16);                         \
      const float vf = __uint_as_float(KV & 0xFFFF0000u);                 \
      float pl = qv * kf + tl * ef;                                       \
      DPPRED(pl);                                                         \
      const float p = exp2f(pl);                                          \
      ssum += p;                                                          \
      accv += p * vf;                                                     \
      accw += p * ef;                                                     \
    }                                                                     \
  } while (0)

__global__ __launch_bounds__(128, 8) void k_attn(
    const unsigned int* __restrict__ QTu, const unsigned int* __restrict__ KVu,
    const unsigned short* __restrict__ Sb, const unsigned short* __restrict__ EAp,
    const int* __restrict__ esrcp, const int* __restrict__ rowptr,
    const float* __restrict__ We, const float* __restrict__ Wb,
    unsigned short* __restrict__ Hout, int n) {
  const int t = threadIdx.x;
  const int lane = t & 63;
  const int node = blockIdx.x * 2 + (t >> 6);
  if (node >= n) return;

  const unsigned int qt = QTu[(size_t)node * 64 + lane];
  const float qv = __uint_as_float(qt << 16) * (SCALEF * LOG2E);
  const float tl = __uint_as_float(qt & 0xFFFF0000u) * LOG2E;
  const int r0 = rowptr[node], r1 = rowptr[node + 1];

  const char* kvbase = (const char*)KVu + 4 * lane;
  const unsigned short* eabase = EAp + (lane & 15);

  float ssum = 0.f, accv = 0.f, accw = 0.f;

  for (int c0 = r0; c0 < r1; c0 += 64) {
    const int mc = min(64, r1 - c0);
    int snv = 0;
    if (lane < mc) snv = esrcp[c0 + lane];

    unsigned int kvA, kvB, kvC, kvD;
    unsigned short eA, eB, eC, eD;
    LOADST(kvA, eA, 0);
    LOADST(kvB, eB, 1);
    LOADST(kvC, eC, 2);
    LOADST(kvD, eD, 3);

    for (int j = 0; j < mc; j += 4) {
      COMPUTE(kvA, eA, j);     LOADST(kvA, eA, j + 4);
      COMPUTE(kvB, eB, j + 1); LOADST(kvB, eB, j + 5);
      COMPUTE(kvC, eC, j + 2); LOADST(kvC, eC, j + 6);
      COMPUTE(kvD, eD, j + 3); LOADST(kvD, eD, j + 7);
    }
  }

  float agg = accv;
  #pragma unroll
  for (int j = 0; j < 16; ++j) {
    const float wj = __shfl(accw, (lane & 48) | j, 64);
    agg += wj * We[j * 64 + lane];
  }
  agg /= (ssum + 1e-16f);

  const float sk = bf2f(Sb[(size_t)node * 64 + lane]);
  float contrib = agg * Wb[lane] + sk * Wb[64 + lane] + (agg - sk) * Wb[128 + lane];
  #pragma unroll
  for (int off = 1; off < 64; off <<= 1) contrib += __shfl_xor(contrib, off, 64);
  const float beta = 1.f / (1.f + __expf(-contrib));
  const float o = beta * sk + (1.f - beta) * agg;
  Hout[(size_t)node * 64 + lane] = f2bf(fmaxf(o, 0.f));
}

// ======================= fused pooling + MLP (one block per graph) =======================
__global__ __launch_bounds__(256) void k_poolmlp(const unsigned short* __restrict__ Hf,
    const int* __restrict__ batch,
    const float* __restrict__ Wlin, const float* __restrict__ blin,
    const float* __restrict__ Wout, const float* __restrict__ bout,
    float* __restrict__ out, int n) {
  const int g = blockIdx.x;
  const int t = threadIdx.x;
  const int lane = t & 63;
  const int w = t >> 6;

  int a = 0, b = n;
  while (a < b) { int mid = (a + b) >> 1; if (batch[mid] < g) a = mid + 1; else b = mid; }
  const int lo = a;
  b = n;
  while (a < b) { int mid = (a + b) >> 1; if (batch[mid] < g + 1) a = mid + 1; else b = mid; }
  const int hi = a;

  float vmax = -1e30f, vsum = 0.f;
  for (int i = lo + w; i < hi; i += 4) {
    const float v = bf2f(Hf[(size_t)i * 64 + lane]);
    vmax = fmaxf(vmax, v);
    vsum += v;
  }
  __shared__ float smax[4][64], ssum[4][64];
  __shared__ float cat[128];
  smax[w][lane] = vmax;
  ssum[w][lane] = vsum;
  __syncthreads();
  if (w == 0) {
    const float mx = fmaxf(fmaxf(smax[0][lane], smax[1][lane]),
                           fmaxf(smax[2][lane], smax[3][lane]));
    const float sm = ssum[0][lane] + ssum[1][lane] + ssum[2][lane] + ssum[3][lane];
    const int cnt = hi - lo;
    cat[lane]      = (cnt > 0) ? mx : 0.f;
    cat[64 + lane] = sm / fmaxf((float)cnt, 1.f);
  }
  __syncthreads();

  float acc = blin[t];
  for (int j = 0; j < 128; ++j) acc += cat[j] * Wlin[j * 256 + t];
  float p = acc * Wout[t];
  #pragma unroll
  for (int off = 1; off < 64; off <<= 1) p += __shfl_xor(p, off, 64);
  __shared__ float red[4];
  if ((t & 63) == 0) red[t >> 6] = p;
  __syncthreads();
  if (t == 0) {
    const float z = red[0] + red[1] + red[2] + red[3] + bout[0];
    out[g] = 1.f / (1.f + __expf(-z));
  }
}

// ======================= launcher =======================
extern "C" void kernel_launch(void* const* d_in, const int* in_sizes, int n_in,
                              void* d_out, int out_size, void* d_ws, size_t ws_size,
                              hipStream_t stream) {
  const float* x     = (const float*)d_in[0];
  const float* ea    = (const float*)d_in[1];
  const int*   eidx  = (const int*)d_in[2];
  const int*   batch = (const int*)d_in[3];
  const float *Wq0 = (const float*)d_in[4],  *bq0 = (const float*)d_in[5];
  const float *Wk0 = (const float*)d_in[6],  *bk0 = (const float*)d_in[7];
  const float *Wv0 = (const float*)d_in[8],  *bv0 = (const float*)d_in[9];
  const float *We0 = (const float*)d_in[10];
  const float *Ws0 = (const float*)d_in[11], *bs0 = (const float*)d_in[12];
  const float *Wb0 = (const float*)d_in[13];
  const float *Wq  = (const float*)d_in[14], *bq  = (const float*)d_in[15];
  const float *Wk  = (const float*)d_in[16], *bk  = (const float*)d_in[17];
  const float *Wv  = (const float*)d_in[18], *bv  = (const float*)d_in[19];
  const float *We  = (const float*)d_in[20];
  const float *Ws  = (const float*)d_in[21], *bs  = (const float*)d_in[22];
  const float *Wb  = (const float*)d_in[23];
  const float *Wlin = (const float*)d_in[24], *blin = (const float*)d_in[25];
  const float *Wout = (const float*)d_in[26], *bout = (const float*)d_in[27];

  const int N = in_sizes[0] / 64;
  const int E = in_sizes[2] / 2;
  const int G = out_size;
  const int* esrc = eidx;
  const int* edst = eidx + E;

  // ---- workspace carve ----
  char* wsp = (char*)d_ws;
  auto alloc = [&](size_t bytes) -> void* {
    void* p = (void*)wsp;
    wsp += (bytes + 255) & ~(size_t)255;
    return p;
  };
  unsigned int* QTu = (unsigned int*)alloc((size_t)N * 64 * 4);        // packed Q|T
  unsigned int* KVu = (unsigned int*)alloc((size_t)N * 64 * 4);        // packed K|V
  unsigned short* Sb16 = (unsigned short*)alloc((size_t)N * 64 * 2);
  unsigned short* Hb16 = (unsigned short*)alloc((size_t)N * 64 * 2);
  unsigned short* Xb16 = (unsigned short*)alloc((size_t)N * 64 * 2);
  int* counts  = (int*)alloc((size_t)N * 4);
  int* rowptr  = (int*)alloc((size_t)(N + 1) * 4);
  int* cursor  = (int*)alloc((size_t)N * 4);
  int* bsums   = (int*)alloc(1024 * 4);
  int* esrcp   = (int*)alloc((size_t)E * 4);
  unsigned short* EAp = (unsigned short*)alloc((size_t)E * 16 * 2);
  float* Wqt   = (float*)alloc(4 * 4096 * 4);
  float* bqt   = (float*)alloc(4 * 64 * 4);
  unsigned short* WT = (unsigned short*)alloc(4 * 5 * 4096 * 2);
  float* bcat  = (float*)alloc(4 * 5 * 64 * 4);

  // ---- CSR build + weight prep ----
  const int gridE = (E + 255) / 256;
  const int NB1 = (N + 1023) / 1024;
  hipMemsetAsync(counts, 0, (size_t)N * 4, stream);
  k_hist<<<gridE, 256, 0, stream>>>(edst, counts, E);
  k_scan1<<<NB1, 1024, 0, stream>>>(counts, rowptr, bsums, N);
  k_scan2<<<1, 64, 0, stream>>>(bsums, NB1);
  k_scan3<<<NB1, 1024, 0, stream>>>(rowptr, cursor, bsums, N, E);
  k_scatperm<<<gridE, 256, 0, stream>>>(esrc, edst, ea, cursor, esrcp, EAp, E);
  k_wqt<<<4, 256, 0, stream>>>(Wq0, bq0, We0, Wq, bq, We, Wqt, bqt);
  k_prep<<<(N * 16 + 255) / 256, 256, 0, stream>>>(
      x, Xb16, N * 16,
      Wq0, Wk0, Wv0, Ws0, Wq, Wk, Wv, Ws, Wqt,
      bq0, bk0, bv0, bs0, bq, bk, bv, bs, bqt, WT, bcat);

  // ---- 4 TransformerConv layers ----
  const int gridLinM = ((N >> 4) + 3) / 4;
  const int gridAttn = (N + 1) / 2;
  for (int l = 0; l < 4; ++l) {
    const float* we_ = (l == 0) ? We0 : We + (l - 1) * 1024;
    const float* wb_ = (l == 0) ? Wb0 : Wb + (l - 1) * 192;
    const unsigned short* xin = (l == 0) ? Xb16 : Hb16;
    k_linm<<<gridLinM, 256, 0, stream>>>(xin, WT + (size_t)l * 20480, bcat + l * 320,
                                         QTu, KVu, Sb16, N);
    k_attn<<<gridAttn, 128, 0, stream>>>(QTu, KVu, Sb16, EAp, esrcp, rowptr,
                                         we_, wb_, Hb16, N);
  }

  // ---- fused pooling + MLP ----
  k_poolmlp<<<G, 256, 0, stream>>>(Hb16, batch, Wlin, blin, Wout, bout,
                                   (float*)d_out, N);
}

// Round 15
// 351.780 us; speedup vs baseline: 1.3527x; 1.0109x over previous
//
#include <hip/hip_runtime.h>
#include <math.h>

#define SCALEF 0.25f            // 1/sqrt(D=16)
#define LOG2E  1.4426950408889634f

typedef __attribute__((ext_vector_type(8))) short short8;
typedef __attribute__((ext_vector_type(4))) float f32x4;

__device__ __forceinline__ unsigned short f2bf(float x) {
  unsigned u = __float_as_uint(x);
  unsigned r = u + 0x7FFFu + ((u >> 16) & 1u);
  return (unsigned short)(r >> 16);
}
__device__ __forceinline__ float bf2f(unsigned short h) {
  return __uint_as_float(((unsigned)h) << 16);
}

// ======================= CSR build =======================
__global__ void k_hist(const int* __restrict__ dst, int* __restrict__ counts, int E) {
  int i = blockIdx.x * 256 + threadIdx.x;
  if (i < E) atomicAdd(&counts[dst[i]], 1);
}

__global__ __launch_bounds__(1024) void k_scan1(const int* __restrict__ counts,
                                                int* __restrict__ excl,
                                                int* __restrict__ bsums, int n) {
  __shared__ int sd[1024];
  int t = threadIdx.x;
  int i = blockIdx.x * 1024 + t;
  int v = (i < n) ? counts[i] : 0;
  sd[t] = v;
  __syncthreads();
  for (int off = 1; off < 1024; off <<= 1) {
    int x = (t >= off) ? sd[t - off] : 0;
    __syncthreads();
    sd[t] += x;
    __syncthreads();
  }
  if (i < n) excl[i] = sd[t] - v;
  if (t == 1023) bsums[blockIdx.x] = sd[1023];
}

// scan3 with scan2 folded in: each block's first wave redundantly scans the
// <=64 block sums to get its own offset (nb = ceil(n/1024) = 49 here).
__global__ __launch_bounds__(1024) void k_scan3(int* __restrict__ rowptr, int* __restrict__ cursor,
                                                const int* __restrict__ bsums, int nb,
                                                int n, int Etot) {
  __shared__ int boff_s;
  const int t = threadIdx.x;
  if (t < 64) {
    int v = (t < nb) ? bsums[t] : 0;
    int incl = v;
    for (int off = 1; off < 64; off <<= 1) {
      int u = __shfl_up(incl, off, 64);
      if (t >= off) incl += u;
    }
    if (t == blockIdx.x) boff_s = incl - v;    // exclusive prefix for this block
  }
  __syncthreads();
  const int boff = boff_s;
  int i = blockIdx.x * 1024 + t;
  if (i < n) { int v = rowptr[i] + boff; rowptr[i] = v; cursor[i] = v; }
  if (i == 0) rowptr[n] = Etot;
}

// scatter edge metadata to CSR slot: 8B int2 {kv byte offset, edge id}.
__global__ void k_scatperm(const int* __restrict__ esrc, const int* __restrict__ edst,
                           int* __restrict__ cursor, int2* __restrict__ eidx2, int E) {
  int i = blockIdx.x * 256 + threadIdx.x;
  if (i >= E) return;
  const int pos = atomicAdd(&cursor[edst[i]], 1);
  eidx2[pos] = make_int2(esrc[i] * 256, i);
}

// ======================= fused prep =======================
// (a) x -> bf16, (b) weight transpose -> bf16 WT (with Wqt computed inline),
// (c) EA gather into CSR order as bf16 (coalesced write, gathered read).
__global__ void k_prep(
    const float* __restrict__ x, unsigned short* __restrict__ xb, int n16,
    const float* __restrict__ Wq0, const float* __restrict__ Wk0, const float* __restrict__ Wv0,
    const float* __restrict__ Ws0,
    const float* __restrict__ Wq, const float* __restrict__ Wk, const float* __restrict__ Wv,
    const float* __restrict__ Ws,
    const float* __restrict__ bq0, const float* __restrict__ bk0, const float* __restrict__ bv0,
    const float* __restrict__ bs0,
    const float* __restrict__ bq, const float* __restrict__ bk, const float* __restrict__ bv,
    const float* __restrict__ bs,
    const float* __restrict__ We0, const float* __restrict__ We,
    unsigned short* __restrict__ WT, float* __restrict__ bcat,
    const float* __restrict__ EA, const int2* __restrict__ eidx2,
    unsigned short* __restrict__ EAp, int E) {
  const int id = blockIdx.x * 256 + threadIdx.x;
  if (id < n16) {
    float4 v = ((const float4*)x)[id];
    ushort4 o;
    o.x = f2bf(v.x); o.y = f2bf(v.y); o.z = f2bf(v.z); o.w = f2bf(v.w);
    ((ushort4*)xb)[id] = o;
  }
  if (id < E) {
    const int eid = eidx2[id].y;
    const float4* s4 = (const float4*)(EA + ((size_t)eid << 4));
    float4 a = s4[0], b = s4[1], c = s4[2], d = s4[3];
    union { unsigned short us[16]; uint4 u4[2]; } o;
    o.us[0] = f2bf(a.x); o.us[1] = f2bf(a.y); o.us[2] = f2bf(a.z); o.us[3] = f2bf(a.w);
    o.us[4] = f2bf(b.x); o.us[5] = f2bf(b.y); o.us[6] = f2bf(b.z); o.us[7] = f2bf(b.w);
    o.us[8] = f2bf(c.x); o.us[9] = f2bf(c.y); o.us[10] = f2bf(c.z); o.us[11] = f2bf(c.w);
    o.us[12] = f2bf(d.x); o.us[13] = f2bf(d.y); o.us[14] = f2bf(d.z); o.us[15] = f2bf(d.w);
    uint4* d4 = (uint4*)(EAp + ((size_t)id << 4));
    d4[0] = o.u4[0]; d4[1] = o.u4[1];
  }
  if (id < 4 * 5 * 4096) {
    const int l = id / 20480;
    const int rem = id - l * 20480;
    const int mat = rem >> 12;
    const int idx = rem & 4095;
    const int k = idx >> 6;
    const int c = idx & 63;
    const float* we = (l == 0) ? We0 : We + (l - 1) * 1024;
    float v;
    if (mat == 0)      v = (l == 0) ? Wq0[idx] : Wq[(l - 1) * 4096 + idx];
    else if (mat == 1) v = (l == 0) ? Wk0[idx] : Wk[(l - 1) * 4096 + idx];
    else if (mat == 2) v = (l == 0) ? Wv0[idx] : Wv[(l - 1) * 4096 + idx];
    else if (mat == 3) v = (l == 0) ? Ws0[idx] : Ws[(l - 1) * 4096 + idx];
    else {             // Wqt = (Wq @ M)*SCALE computed inline
      const float* wq = (l == 0) ? Wq0 : Wq + (l - 1) * 4096;
      const int hb = c & 48;
      float s = 0.f;
      #pragma unroll
      for (int d = 0; d < 16; ++d) s += wq[k * 64 + hb + d] * we[(c & 15) * 64 + hb + d];
      v = s * SCALEF;
    }
    WT[(size_t)(l * 5 + mat) * 4096 + c * 64 + k] = f2bf(v);
    if (k == 0) {
      float b;
      if (mat == 0)      b = (l == 0) ? bq0[c] : bq[(l - 1) * 64 + c];
      else if (mat == 1) b = (l == 0) ? bk0[c] : bk[(l - 1) * 64 + c];
      else if (mat == 2) b = (l == 0) ? bv0[c] : bv[(l - 1) * 64 + c];
      else if (mat == 3) b = (l == 0) ? bs0[c] : bs[(l - 1) * 64 + c];
      else {             // bqt inline
        const float* bqv = (l == 0) ? bq0 : bq + (l - 1) * 64;
        const int hb = c & 48;
        float s = 0.f;
        #pragma unroll
        for (int d = 0; d < 16; ++d) s += bqv[hb + d] * we[(c & 15) * 64 + hb + d];
        b = s * SCALEF;
      }
      bcat[(l * 5 + mat) * 64 + c] = b;
    }
  }
}

// ======================= node linear via MFMA =======================
__device__ __forceinline__ void mat_gemm(const unsigned short* __restrict__ wb,
                                         const short8 a0, const short8 a1,
                                         f32x4 acc[4]) {
  #pragma unroll
  for (int cf = 0; cf < 4; ++cf) {
    short8 b0 = *(const short8*)(wb + cf * 1024);
    short8 b1 = *(const short8*)(wb + cf * 1024 + 32);
    acc[cf] = __builtin_amdgcn_mfma_f32_16x16x32_bf16(a0, b0, acc[cf], 0, 0, 0);
    acc[cf] = __builtin_amdgcn_mfma_f32_16x16x32_bf16(a1, b1, acc[cf], 0, 0, 0);
  }
}

__global__ __launch_bounds__(256) void k_linm(
    const unsigned short* __restrict__ Xb, const unsigned short* __restrict__ WT,
    const float* __restrict__ bcat,
    unsigned int* __restrict__ QTu, unsigned int* __restrict__ KVu,
    unsigned short* __restrict__ Sb, int n) {
  const int lane = threadIdx.x & 63;
  const int tile = blockIdx.x * 4 + (threadIdx.x >> 6);
  const int ntr = n >> 4;                    // N % 16 == 0
  if (tile >= ntr) return;
  const int r0 = tile << 4;
  const int c15 = lane & 15;
  const int kg = lane >> 4;                  // 0..3
  const int rbase = r0 + kg * 4;

  const unsigned short* xrow = Xb + (size_t)(r0 + c15) * 64 + kg * 8;
  const short8 a0 = *(const short8*)(xrow);
  const short8 a1 = *(const short8*)(xrow + 32);
  const f32x4 z = {0.f, 0.f, 0.f, 0.f};

  // ---- pair (K=mat1, V=mat2) -> packed KVu ----
  {
    f32x4 aK[4] = {z, z, z, z}, aV[4] = {z, z, z, z};
    mat_gemm(WT + (1 << 12) + (size_t)c15 * 64 + kg * 8, a0, a1, aK);
    mat_gemm(WT + (2 << 12) + (size_t)c15 * 64 + kg * 8, a0, a1, aV);
    #pragma unroll
    for (int cf = 0; cf < 4; ++cf) {
      const float bk_ = bcat[1 * 64 + cf * 16 + c15];
      const float bv_ = bcat[2 * 64 + cf * 16 + c15];
      #pragma unroll
      for (int reg = 0; reg < 4; ++reg) {
        const unsigned pk = f2bf(aK[cf][reg] + bk_);
        const unsigned pv = f2bf(aV[cf][reg] + bv_);
        KVu[(size_t)(rbase + reg) * 64 + cf * 16 + c15] = pk | (pv << 16);
      }
    }
  }

  // ---- pair (Q=mat0, T=mat4) -> packed QTu ----
  {
    f32x4 aQ[4] = {z, z, z, z}, aT[4] = {z, z, z, z};
    mat_gemm(WT + (0 << 12) + (size_t)c15 * 64 + kg * 8, a0, a1, aQ);
    mat_gemm(WT + ((size_t)4 << 12) + (size_t)c15 * 64 + kg * 8, a0, a1, aT);
    #pragma unroll
    for (int cf = 0; cf < 4; ++cf) {
      const float bq_ = bcat[0 * 64 + cf * 16 + c15];
      const float bt_ = bcat[4 * 64 + cf * 16 + c15];
      #pragma unroll
      for (int reg = 0; reg < 4; ++reg) {
        const unsigned pq = f2bf(aQ[cf][reg] + bq_);
        const unsigned pt = f2bf(aT[cf][reg] + bt_);
        QTu[(size_t)(rbase + reg) * 64 + cf * 16 + c15] = pq | (pt << 16);
      }
    }
  }

  // ---- S = mat3 (ushort) ----
  {
    f32x4 aS[4] = {z, z, z, z};
    mat_gemm(WT + ((size_t)3 << 12) + (size_t)c15 * 64 + kg * 8, a0, a1, aS);
    #pragma unroll
    for (int cf = 0; cf < 4; ++cf) {
      const float bs_ = bcat[3 * 64 + cf * 16 + c15];
      #pragma unroll
      for (int reg = 0; reg < 4; ++reg) {
        Sb[(size_t)(rbase + reg) * 64 + cf * 16 + c15] = f2bf(aS[cf][reg] + bs_);
      }
    }
  }
}

// ======================= fused edge/attention kernel =======================
// One wave per dst node, block = 2 waves, no LDS in hot loop. DPP head-group
// reduce, exp2 with folded log2e, packed KV/QT dwords. Straight-line
// predication: padded pipeline slots get logit -1e30 -> p = 0.
#define DPPRED(pl) do {                                                           \
    pl += __int_as_float(__builtin_amdgcn_update_dpp(0, __float_as_int(pl),       \
                                                     0xB1, 0xF, 0xF, true));      \
    pl += __int_as_float(__builtin_amdgcn_update_dpp(0, __float_as_int(pl),       \
                                                     0x4E, 0xF, 0xF, true));      \
    pl += __int_as_float(__builtin_amdgcn_update_dpp(0, __float_as_int(pl),       \
                                                     0x124, 0xF, 0xF, true));     \
    pl += __int_as_float(__builtin_amdgcn_update_dpp(0, __float_as_int(pl),       \
                                                     0x128, 0xF, 0xF, true));     \
  } while (0)

#define LOADST(KV, EE, jj) do {                                           \
    int jc_ = (jj) < mc ? (jj) : mc - 1;                                  \
    int off_ = __builtin_amdgcn_readlane(snv, jc_);                       \
    KV = *(const unsigned int*)(kvbase + off_);                           \
    EE = eabase[(size_t)(c0 + jc_) << 4];                                 \
  } while (0)

#define COMPUTE(KV, EE, jj) do {                                          \
    const float sel = ((jj) < mc) ? 0.f : -1e30f;                         \
    const float ef = bf2f(EE);                                            \
    const float kf = __uint_as_float(KV << 16);                           \
    const float vf = __uint_as_float(KV & 0xFFFF0000u);                   \
    float pl = qv * kf + tl * ef;                                         \
    DPPRED(pl);                                                           \
    const float p = exp2f(pl + sel);                                      \
    ssum += p;                                                            \
    accv += p * vf;                                                       \
    accw += p * ef;                                                       \
  } while (0)

__global__ __launch_bounds__(128, 8) void k_attn(
    const unsigned int* __restrict__ QTu, const unsigned int* __restrict__ KVu,
    const unsigned short* __restrict__ Sb, const unsigned short* __restrict__ EAp,
    const int2* __restrict__ eidx2, const int* __restrict__ rowptr,
    const float* __restrict__ We, const float* __restrict__ Wb,
    unsigned short* __restrict__ Hout, int n) {
  const int t = threadIdx.x;
  const int lane = t & 63;
  const int node = blockIdx.x * 2 + (t >> 6);
  if (node >= n) return;

  const unsigned int qt = QTu[(size_t)node * 64 + lane];
  const float qv = __uint_as_float(qt << 16) * (SCALEF * LOG2E);
  const float tl = __uint_as_float(qt & 0xFFFF0000u) * LOG2E;
  const int r0 = rowptr[node], r1 = rowptr[node + 1];

  const char* kvbase = (const char*)KVu + 4 * lane;
  const unsigned short* eabase = EAp + (lane & 15);

  float ssum = 0.f, accv = 0.f, accw = 0.f;

  for (int c0 = r0; c0 < r1; c0 += 64) {
    const int mc = min(64, r1 - c0);
    int snv = 0;
    if (lane < mc) snv = eidx2[c0 + lane].x;

    unsigned int kvA, kvB, kvC, kvD;
    unsigned short eA, eB, eC, eD;
    LOADST(kvA, eA, 0);
    LOADST(kvB, eB, 1);
    LOADST(kvC, eC, 2);
    LOADST(kvD, eD, 3);

    for (int j = 0; j < mc; j += 4) {
      COMPUTE(kvA, eA, j);     LOADST(kvA, eA, j + 4);
      COMPUTE(kvB, eB, j + 1); LOADST(kvB, eB, j + 5);
      COMPUTE(kvC, eC, j + 2); LOADST(kvC, eC, j + 6);
      COMPUTE(kvD, eD, j + 3); LOADST(kvD, eD, j + 7);
    }
  }

  float agg = accv;
  #pragma unroll
  for (int j = 0; j < 16; ++j) {
    const float wj = __shfl(accw, (lane & 48) | j, 64);
    agg += wj * We[j * 64 + lane];
  }
  agg /= (ssum + 1e-16f);

  const float sk = bf2f(Sb[(size_t)node * 64 + lane]);
  float contrib = agg * Wb[lane] + sk * Wb[64 + lane] + (agg - sk) * Wb[128 + lane];
  #pragma unroll
  for (int off = 1; off < 64; off <<= 1) contrib += __shfl_xor(contrib, off, 64);
  const float beta = 1.f / (1.f + __expf(-contrib));
  const float o = beta * sk + (1.f - beta) * agg;
  Hout[(size_t)node * 64 + lane] = f2bf(fmaxf(o, 0.f));
}

// ======================= fused pooling + MLP (one block per graph) =======================
__global__ __launch_bounds__(256) void k_poolmlp(const unsigned short* __restrict__ Hf,
    const int* __restrict__ batch,
    const float* __restrict__ Wlin, const float* __restrict__ blin,
    const float* __restrict__ Wout, const float* __restrict__ bout,
    float* __restrict__ out, int n) {
  const int g = blockIdx.x;
  const int t = threadIdx.x;
  const int lane = t & 63;
  const int w = t >> 6;

  int a = 0, b = n;
  while (a < b) { int mid = (a + b) >> 1; if (batch[mid] < g) a = mid + 1; else b = mid; }
  const int lo = a;
  b = n;
  while (a < b) { int mid = (a + b) >> 1; if (batch[mid] < g + 1) a = mid + 1; else b = mid; }
  const int hi = a;

  float vmax = -1e30f, vsum = 0.f;
  for (int i = lo + w; i < hi; i += 4) {
    const float v = bf2f(Hf[(size_t)i * 64 + lane]);
    vmax = fmaxf(vmax, v);
    vsum += v;
  }
  __shared__ float smax[4][64], ssum[4][64];
  __shared__ float cat[128];
  smax[w][lane] = vmax;
  ssum[w][lane] = vsum;
  __syncthreads();
  if (w == 0) {
    const float mx = fmaxf(fmaxf(smax[0][lane], smax[1][lane]),
                           fmaxf(smax[2][lane], smax[3][lane]));
    const float sm = ssum[0][lane] + ssum[1][lane] + ssum[2][lane] + ssum[3][lane];
    const int cnt = hi - lo;
    cat[lane]      = (cnt > 0) ? mx : 0.f;
    cat[64 + lane] = sm / fmaxf((float)cnt, 1.f);
  }
  __syncthreads();

  float acc = blin[t];
  for (int j = 0; j < 128; ++j) acc += cat[j] * Wlin[j * 256 + t];
  float p = acc * Wout[t];
  #pragma unroll
  for (int off = 1; off < 64; off <<= 1) p += __shfl_xor(p, off, 64);
  __shared__ float red[4];
  if ((t & 63) == 0) red[t >> 6] = p;
  __syncthreads();
  if (t == 0) {
    const float z = red[0] + red[1] + red[2] + red[3] + bout[0];
    out[g] = 1.f / (1.f + __expf(-z));
  }
}

// ======================= launcher =======================
extern "C" void kernel_launch(void* const* d_in, const int* in_sizes, int n_in,
                              void* d_out, int out_size, void* d_ws, size_t ws_size,
                              hipStream_t stream) {
  const float* x     = (const float*)d_in[0];
  const float* ea    = (const float*)d_in[1];
  const int*   eidx  = (const int*)d_in[2];
  const int*   batch = (const int*)d_in[3];
  const float *Wq0 = (const float*)d_in[4],  *bq0 = (const float*)d_in[5];
  const float *Wk0 = (const float*)d_in[6],  *bk0 = (const float*)d_in[7];
  const float *Wv0 = (const float*)d_in[8],  *bv0 = (const float*)d_in[9];
  const float *We0 = (const float*)d_in[10];
  const float *Ws0 = (const float*)d_in[11], *bs0 = (const float*)d_in[12];
  const float *Wb0 = (const float*)d_in[13];
  const float *Wq  = (const float*)d_in[14], *bq  = (const float*)d_in[15];
  const float *Wk  = (const float*)d_in[16], *bk  = (const float*)d_in[17];
  const float *Wv  = (const float*)d_in[18], *bv  = (const float*)d_in[19];
  const float *We  = (const float*)d_in[20];
  const float *Ws  = (const float*)d_in[21], *bs  = (const float*)d_in[22];
  const float *Wb  = (const float*)d_in[23];
  const float *Wlin = (const float*)d_in[24], *blin = (const float*)d_in[25];
  const float *Wout = (const float*)d_in[26], *bout = (const float*)d_in[27];

  const int N = in_sizes[0] / 64;
  const int E = in_sizes[2] / 2;
  const int G = out_size;
  const int* esrc = eidx;
  const int* edst = eidx + E;

  // ---- workspace carve ----
  char* wsp = (char*)d_ws;
  auto alloc = [&](size_t bytes) -> void* {
    void* p = (void*)wsp;
    wsp += (bytes + 255) & ~(size_t)255;
    return p;
  };
  unsigned int* QTu = (unsigned int*)alloc((size_t)N * 64 * 4);        // packed Q|T
  unsigned int* KVu = (unsigned int*)alloc((size_t)N * 64 * 4);        // packed K|V
  unsigned short* Sb16 = (unsigned short*)alloc((size_t)N * 64 * 2);
  unsigned short* Hb16 = (unsigned short*)alloc((size_t)N * 64 * 2);
  unsigned short* Xb16 = (unsigned short*)alloc((size_t)N * 64 * 2);
  int* counts  = (int*)alloc((size_t)N * 4);
  int* rowptr  = (int*)alloc((size_t)(N + 1) * 4);
  int* cursor  = (int*)alloc((size_t)N * 4);
  int* bsums   = (int*)alloc(1024 * 4);
  int2* eidx2  = (int2*)alloc((size_t)E * 8);
  unsigned short* EAp = (unsigned short*)alloc((size_t)E * 16 * 2);
  unsigned short* WT = (unsigned short*)alloc(4 * 5 * 4096 * 2);
  float* bcat  = (float*)alloc(4 * 5 * 64 * 4);

  // ---- CSR build + fused prep ----
  const int gridE = (E + 255) / 256;
  const int NB1 = (N + 1023) / 1024;
  hipMemsetAsync(counts, 0, (size_t)N * 4, stream);
  k_hist<<<gridE, 256, 0, stream>>>(edst, counts, E);
  k_scan1<<<NB1, 1024, 0, stream>>>(counts, rowptr, bsums, N);
  k_scan3<<<NB1, 1024, 0, stream>>>(rowptr, cursor, bsums, NB1, N, E);
  k_scatperm<<<gridE, 256, 0, stream>>>(esrc, edst, cursor, eidx2, E);
  const int n16 = N * 16;
  k_prep<<<(n16 + 255) / 256, 256, 0, stream>>>(
      x, Xb16, n16,
      Wq0, Wk0, Wv0, Ws0, Wq, Wk, Wv, Ws,
      bq0, bk0, bv0, bs0, bq, bk, bv, bs,
      We0, We, WT, bcat, ea, eidx2, EAp, E);

  // ---- 4 TransformerConv layers ----
  const int gridLinM = ((N >> 4) + 3) / 4;
  const int gridAttn = (N + 1) / 2;
  for (int l = 0; l < 4; ++l) {
    const float* we_ = (l == 0) ? We0 : We + (l - 1) * 1024;
    const float* wb_ = (l == 0) ? Wb0 : Wb + (l - 1) * 192;
    const unsigned short* xin = (l == 0) ? Xb16 : Hb16;
    k_linm<<<gridLinM, 256, 0, stream>>>(xin, WT + (size_t)l * 20480, bcat + l * 320,
                                         QTu, KVu, Sb16, N);
    k_attn<<<gridAttn, 128, 0, stream>>>(QTu, KVu, Sb16, EAp, eidx2, rowptr,
                                         we_, wb_, Hb16, N);
  }

  // ---- fused pooling + MLP ----
  k_poolmlp<<<G, 256, 0, stream>>>(Hb16, batch, Wlin, blin, Wout, bout,
                                   (float*)d_out, N);
}